// Round 1
// baseline (397.711 us; speedup 1.0000x reference)
//
#include <hip/hip_runtime.h>

// Problem constants (from reference): SIZE = (D,H,W) = (160,192,160), B=2, C=2.
#define DD 160
#define HH 192
#define WW 160
#define SP (DD * HH * WW)          // 4,915,200 spatial voxels per batch
#define NB 2
#define NC 2

__global__ __launch_bounds__(256) void st_warp_kernel(
    const float* __restrict__ src,   // [B, C, D, H, W]
    const float* __restrict__ flow,  // [B, 3, D, H, W]
    float* __restrict__ out)         // [B, C, D, H, W]
{
    int idx = blockIdx.x * blockDim.x + threadIdx.x;   // over B*SP = 9,830,400
    const int total = NB * SP;
    if (idx >= total) return;

    int b  = idx / SP;
    int sp = idx - b * SP;
    int x  = sp % WW;
    int t  = sp / WW;
    int y  = t % HH;
    int z  = t / HH;

    // Sample position in voxel coords: grid + flow (normalization cancels).
    const float* fb = flow + b * 3 * SP + sp;
    float sx = (float)x + fb[0];
    float sy = (float)y + fb[SP];
    float sz = (float)z + fb[2 * SP];

    float xf = floorf(sx), yf = floorf(sy), zf = floorf(sz);
    float fx = sx - xf, fy = sy - yf, fz = sz - zf;
    int x0 = (int)xf, y0 = (int)yf, z0 = (int)zf;
    int x1 = x0 + 1, y1 = y0 + 1, z1 = z0 + 1;

    // Per-corner weights, zeroed when that corner is out of bounds
    // (padding_mode='zeros' with align_corners=True semantics).
    float wx0 = (x0 >= 0 && x0 < WW) ? (1.0f - fx) : 0.0f;
    float wx1 = (x1 >= 0 && x1 < WW) ? fx : 0.0f;
    float wy0 = (y0 >= 0 && y0 < HH) ? (1.0f - fy) : 0.0f;
    float wy1 = (y1 >= 0 && y1 < HH) ? fy : 0.0f;
    float wz0 = (z0 >= 0 && z0 < DD) ? (1.0f - fz) : 0.0f;
    float wz1 = (z1 >= 0 && z1 < DD) ? fz : 0.0f;

    // Clamped indices for the gather.
    int cx0 = min(max(x0, 0), WW - 1);
    int cx1 = min(max(x1, 0), WW - 1);
    int cy0 = min(max(y0, 0), HH - 1);
    int cy1 = min(max(y1, 0), HH - 1);
    int cz0 = min(max(z0, 0), DD - 1);
    int cz1 = min(max(z1, 0), DD - 1);

    // Row base offsets for the 4 (z,y) combinations.
    int o00 = (cz0 * HH + cy0) * WW;
    int o01 = (cz0 * HH + cy1) * WW;
    int o10 = (cz1 * HH + cy0) * WW;
    int o11 = (cz1 * HH + cy1) * WW;

    float w00 = wz0 * wy0;
    float w01 = wz0 * wy1;
    float w10 = wz1 * wy0;
    float w11 = wz1 * wy1;

    const float* s0 = src + b * NC * SP;  // channel 0
    const float* s1 = s0 + SP;            // channel 1

    float acc0 = 0.0f, acc1 = 0.0f;

    {   // z0 y0 x0
        int o = o00 + cx0; float w = w00 * wx0;
        acc0 += w * s0[o]; acc1 += w * s1[o];
    }
    {   // z0 y0 x1
        int o = o00 + cx1; float w = w00 * wx1;
        acc0 += w * s0[o]; acc1 += w * s1[o];
    }
    {   // z0 y1 x0
        int o = o01 + cx0; float w = w01 * wx0;
        acc0 += w * s0[o]; acc1 += w * s1[o];
    }
    {   // z0 y1 x1
        int o = o01 + cx1; float w = w01 * wx1;
        acc0 += w * s0[o]; acc1 += w * s1[o];
    }
    {   // z1 y0 x0
        int o = o10 + cx0; float w = w10 * wx0;
        acc0 += w * s0[o]; acc1 += w * s1[o];
    }
    {   // z1 y0 x1
        int o = o10 + cx1; float w = w10 * wx1;
        acc0 += w * s0[o]; acc1 += w * s1[o];
    }
    {   // z1 y1 x0
        int o = o11 + cx0; float w = w11 * wx0;
        acc0 += w * s0[o]; acc1 += w * s1[o];
    }
    {   // z1 y1 x1
        int o = o11 + cx1; float w = w11 * wx1;
        acc0 += w * s0[o]; acc1 += w * s1[o];
    }

    float* ob = out + b * NC * SP + sp;
    ob[0]  = acc0;
    ob[SP] = acc1;
}

extern "C" void kernel_launch(void* const* d_in, const int* in_sizes, int n_in,
                              void* d_out, int out_size, void* d_ws, size_t ws_size,
                              hipStream_t stream) {
    const float* src  = (const float*)d_in[0];
    const float* flow = (const float*)d_in[1];
    float* out = (float*)d_out;

    const int total = NB * SP;            // 9,830,400 threads
    const int block = 256;
    const int grid  = (total + block - 1) / block;  // 38,400 blocks
    st_warp_kernel<<<grid, block, 0, stream>>>(src, flow, out);
}

// Round 3
// 383.942 us; speedup vs baseline: 1.0359x; 1.0359x over previous
//
#include <hip/hip_runtime.h>

// SIZE = (D,H,W) = (160,192,160), B=2, C=2.
#define DD 160
#define HH 192
#define WW 160
#define SP (DD * HH * WW)          // 4,915,200 spatial voxels per batch
#define NB 2
#define NC 2

typedef float v2f __attribute__((ext_vector_type(2)));

__device__ __forceinline__ v2f ld2_nt(const float* p) {
    // 8B nontemporal vector load (flow is read-once streaming).
    return __builtin_nontemporal_load(reinterpret_cast<const v2f*>(p));
}
__device__ __forceinline__ void st2_nt(float* p, float a, float b) {
    v2f v = {a, b};
    __builtin_nontemporal_store(v, reinterpret_cast<v2f*>(p));
}
__device__ __forceinline__ v2f ld2g(const float* p) {
    // gather pair load — keep cacheable (neighboring threads reuse lines)
    return *reinterpret_cast<const v2f*>(p);
}

// One trilinear sample at (x+dx, y+dy, z+dz) for both channels.
__device__ __forceinline__ void sample_one(
    const float* __restrict__ s0, const float* __restrict__ s1,
    int x, int y, int z, float dx, float dy, float dz,
    float& a0, float& a1)
{
    float sx = (float)x + dx;
    float sy = (float)y + dy;
    float sz = (float)z + dz;

    float xf = floorf(sx), yf = floorf(sy), zf = floorf(sz);
    float fx = sx - xf, fy = sy - yf, fz = sz - zf;
    int x0 = (int)xf, y0 = (int)yf, z0 = (int)zf;
    int x1 = x0 + 1, y1 = y0 + 1, z1 = z0 + 1;

    // Weights zeroed when corner OOB (padding_mode='zeros').
    float wx0 = (x0 >= 0 && x0 < WW) ? (1.0f - fx) : 0.0f;
    float wx1 = (x1 >= 0 && x1 < WW) ? fx : 0.0f;
    float wy0 = (y0 >= 0 && y0 < HH) ? (1.0f - fy) : 0.0f;
    float wy1 = (y1 >= 0 && y1 < HH) ? fy : 0.0f;
    float wz0 = (z0 >= 0 && z0 < DD) ? (1.0f - fz) : 0.0f;
    float wz1 = (z1 >= 0 && z1 < DD) ? fz : 0.0f;

    // Pair base: load {val[p], val[p+1]}; select per clamped index.
    int p  = min(max(x0, 0), WW - 2);
    int i0 = min(max(x0, 0), WW - 1) - p;   // 0 or 1
    int i1 = min(max(x1, 0), WW - 1) - p;   // 0 or 1

    int cy0 = min(max(y0, 0), HH - 1);
    int cy1 = min(max(y1, 0), HH - 1);
    int cz0 = min(max(z0, 0), DD - 1);
    int cz1 = min(max(z1, 0), DD - 1);

    int o00 = (cz0 * HH + cy0) * WW + p;
    int o01 = (cz0 * HH + cy1) * WW + p;
    int o10 = (cz1 * HH + cy0) * WW + p;
    int o11 = (cz1 * HH + cy1) * WW + p;

    float w00 = wz0 * wy0;
    float w01 = wz0 * wy1;
    float w10 = wz1 * wy0;
    float w11 = wz1 * wy1;

    // Issue all 8 pair-gathers (independent → deep MLP).
    v2f c0_00 = ld2g(s0 + o00); v2f c1_00 = ld2g(s1 + o00);
    v2f c0_01 = ld2g(s0 + o01); v2f c1_01 = ld2g(s1 + o01);
    v2f c0_10 = ld2g(s0 + o10); v2f c1_10 = ld2g(s1 + o10);
    v2f c0_11 = ld2g(s0 + o11); v2f c1_11 = ld2g(s1 + o11);

    #define PICK(v, i) ((i) ? (v).y : (v).x)
    float r0, r1;
    r0  = w00 * (wx0 * PICK(c0_00, i0) + wx1 * PICK(c0_00, i1));
    r1  = w00 * (wx0 * PICK(c1_00, i0) + wx1 * PICK(c1_00, i1));
    r0 += w01 * (wx0 * PICK(c0_01, i0) + wx1 * PICK(c0_01, i1));
    r1 += w01 * (wx0 * PICK(c1_01, i0) + wx1 * PICK(c1_01, i1));
    r0 += w10 * (wx0 * PICK(c0_10, i0) + wx1 * PICK(c0_10, i1));
    r1 += w10 * (wx0 * PICK(c1_10, i0) + wx1 * PICK(c1_10, i1));
    r0 += w11 * (wx0 * PICK(c0_11, i0) + wx1 * PICK(c0_11, i1));
    r1 += w11 * (wx0 * PICK(c1_11, i0) + wx1 * PICK(c1_11, i1));
    #undef PICK

    a0 = r0;
    a1 = r1;
}

__global__ __launch_bounds__(256) void st_warp_kernel(
    const float* __restrict__ src,   // [B, C, D, H, W]
    const float* __restrict__ flow,  // [B, 3, D, H, W]
    float* __restrict__ out)         // [B, C, D, H, W]
{
    const int half = SP / 2;
    int i = blockIdx.x * blockDim.x + threadIdx.x;   // over B*SP/2
    if (i >= NB * half) return;

    int b  = i / half;
    int r  = i - b * half;
    int sp = r * 2;                  // even → float2-aligned flow/out

    int x  = sp % WW;                // even, x+1 < WW (WW even)
    int t  = sp / WW;
    int y  = t % HH;
    int z  = t / HH;

    const float* fb = flow + b * 3 * SP + sp;
    v2f dx2 = ld2_nt(fb);
    v2f dy2 = ld2_nt(fb + SP);
    v2f dz2 = ld2_nt(fb + 2 * SP);

    const float* s0 = src + b * NC * SP;
    const float* s1 = s0 + SP;

    float a0A, a1A, a0B, a1B;
    sample_one(s0, s1, x,     y, z, dx2.x, dy2.x, dz2.x, a0A, a1A);
    sample_one(s0, s1, x + 1, y, z, dx2.y, dy2.y, dz2.y, a0B, a1B);

    float* ob = out + b * NC * SP + sp;
    st2_nt(ob,      a0A, a0B);
    st2_nt(ob + SP, a1A, a1B);
}

extern "C" void kernel_launch(void* const* d_in, const int* in_sizes, int n_in,
                              void* d_out, int out_size, void* d_ws, size_t ws_size,
                              hipStream_t stream) {
    const float* src  = (const float*)d_in[0];
    const float* flow = (const float*)d_in[1];
    float* out = (float*)d_out;

    const int total = NB * SP / 2;        // 4,915,200 threads
    const int block = 256;
    const int grid  = (total + block - 1) / block;
    st_warp_kernel<<<grid, block, 0, stream>>>(src, flow, out);
}

// Round 4
// 279.841 us; speedup vs baseline: 1.4212x; 1.3720x over previous
//
#include <hip/hip_runtime.h>

// SIZE = (D,H,W) = (160,192,160), B=2, C=2.
#define DD 160
#define HH 192
#define WW 160
#define SP (DD * HH * WW)
#define NB 2
#define NC 2

// Tile per block (x,y,z) and staged region (edge-replicated halo).
#define TX 32
#define TY 8
#define TZ 4
#define RXW 40                 // x region: [X0-4, X0+35]  (supports dx in [-4,4))
#define RYH 15                 // y region: [Y0-3, Y0+11]  (supports dy in [-3,4))
#define RZD 11                 // z region: [Z0-3, Z0+7]   (supports dz in [-3,4))
#define REGC (RZD * RYH * RXW) // 6600 floats per channel
#define NCHUNK (2 * REGC / 4)  // 3300 float4 staging chunks
#define NITER 13               // ceil(3300/256)

#define NTX 5                  // 160/32 tiles in x
#define NTY 24                 // 192/8
#define NTZ 40                 // 160/4
#define NTILES (NTX * NTY * NTZ * NB)   // 9600
#define PER_XCD (NTILES / 8)            // 1200

typedef float v2f __attribute__((ext_vector_type(2)));
typedef float v4f __attribute__((ext_vector_type(4)));

__device__ __forceinline__ v4f ld4_nt(const float* p) {
    return __builtin_nontemporal_load(reinterpret_cast<const v4f*>(p));
}
__device__ __forceinline__ void st4_nt(float* p, v4f v) {
    __builtin_nontemporal_store(v, reinterpret_cast<v4f*>(p));
}
__device__ __forceinline__ v2f ld2g(const float* p) {
    return *reinterpret_cast<const v2f*>(p);
}

// Validated round-3 global-memory trilinear sample (fallback path).
__device__ __forceinline__ void sample_global(
    const float* __restrict__ s0, const float* __restrict__ s1,
    int x, int y, int z, float dx, float dy, float dz,
    float& a0, float& a1)
{
    float sx = (float)x + dx, sy = (float)y + dy, sz = (float)z + dz;
    float xf = floorf(sx), yf = floorf(sy), zf = floorf(sz);
    float fx = sx - xf, fy = sy - yf, fz = sz - zf;
    int x0 = (int)xf, y0 = (int)yf, z0 = (int)zf;
    int x1 = x0 + 1, y1 = y0 + 1, z1 = z0 + 1;

    float wx0 = (x0 >= 0 && x0 < WW) ? (1.0f - fx) : 0.0f;
    float wx1 = (x1 >= 0 && x1 < WW) ? fx : 0.0f;
    float wy0 = (y0 >= 0 && y0 < HH) ? (1.0f - fy) : 0.0f;
    float wy1 = (y1 >= 0 && y1 < HH) ? fy : 0.0f;
    float wz0 = (z0 >= 0 && z0 < DD) ? (1.0f - fz) : 0.0f;
    float wz1 = (z1 >= 0 && z1 < DD) ? fz : 0.0f;

    int p  = min(max(x0, 0), WW - 2);
    int i0 = min(max(x0, 0), WW - 1) - p;
    int i1 = min(max(x1, 0), WW - 1) - p;
    int cy0 = min(max(y0, 0), HH - 1), cy1 = min(max(y1, 0), HH - 1);
    int cz0 = min(max(z0, 0), DD - 1), cz1 = min(max(z1, 0), DD - 1);

    int o00 = (cz0 * HH + cy0) * WW + p;
    int o01 = (cz0 * HH + cy1) * WW + p;
    int o10 = (cz1 * HH + cy0) * WW + p;
    int o11 = (cz1 * HH + cy1) * WW + p;

    float w00 = wz0 * wy0, w01 = wz0 * wy1, w10 = wz1 * wy0, w11 = wz1 * wy1;

    v2f c0_00 = ld2g(s0 + o00); v2f c1_00 = ld2g(s1 + o00);
    v2f c0_01 = ld2g(s0 + o01); v2f c1_01 = ld2g(s1 + o01);
    v2f c0_10 = ld2g(s0 + o10); v2f c1_10 = ld2g(s1 + o10);
    v2f c0_11 = ld2g(s0 + o11); v2f c1_11 = ld2g(s1 + o11);

    #define PICK(v, i) ((i) ? (v).y : (v).x)
    float r0, r1;
    r0  = w00 * (wx0 * PICK(c0_00, i0) + wx1 * PICK(c0_00, i1));
    r1  = w00 * (wx0 * PICK(c1_00, i0) + wx1 * PICK(c1_00, i1));
    r0 += w01 * (wx0 * PICK(c0_01, i0) + wx1 * PICK(c0_01, i1));
    r1 += w01 * (wx0 * PICK(c1_01, i0) + wx1 * PICK(c1_01, i1));
    r0 += w10 * (wx0 * PICK(c0_10, i0) + wx1 * PICK(c0_10, i1));
    r1 += w10 * (wx0 * PICK(c1_10, i0) + wx1 * PICK(c1_10, i1));
    r0 += w11 * (wx0 * PICK(c0_11, i0) + wx1 * PICK(c0_11, i1));
    r1 += w11 * (wx0 * PICK(c1_11, i0) + wx1 * PICK(c1_11, i1));
    #undef PICK
    a0 = r0; a1 = r1;
}

__global__ __launch_bounds__(256, 3) void st_warp_kernel(
    const float* __restrict__ src,   // [B, C, D, H, W]
    const float* __restrict__ flow,  // [B, 3, D, H, W]
    float* __restrict__ out)         // [B, C, D, H, W]
{
    __shared__ float sbuf[2 * REGC];   // 52,800 B -> 3 blocks/CU

    // XCD-aware swizzle: each XCD gets a contiguous range of tile ids
    // (tile order x-fastest, then y, z, b) => contiguous z-slabs per XCD.
    int u   = blockIdx.x;
    int tl  = (u & 7) * PER_XCD + (u >> 3);
    int tx  = tl % NTX;  int t2 = tl / NTX;
    int ty  = t2 % NTY;  int t3 = t2 / NTY;
    int tz  = t3 % NTZ;  int b  = t3 / NTZ;
    int X0 = tx * TX, Y0 = ty * TY, Z0 = tz * TZ;
    int tid = threadIdx.x;

    const float* sb = src + b * NC * SP;  // channel 0 base
    const float* s1g = sb + SP;           // channel 1 base

    // ---- Stage region (edge-replicated) : issue all global loads first ----
    v4f vals[NITER];
    int  laddr[NITER];
    #pragma unroll
    for (int i = 0; i < NITER; ++i) {
        int c = tid + i * 256;
        if (i < NITER - 1 || c < NCHUNK) {
            int ch  = (c >= REGC / 4) ? 1 : 0;       // REGC/4 = 1650
            int rem = c - ch * (REGC / 4);
            int lz  = rem / (RYH * RXW / 4);         // /150, [0,10]
            int r2  = rem - lz * (RYH * RXW / 4);
            int ly  = r2 / (RXW / 4);                // /10, [0,14]
            int lxc = r2 - ly * (RXW / 4);           // [0,9]
            int mz = min(max(Z0 - 3 + lz, 0), DD - 1);
            int my = min(max(Y0 - 3 + ly, 0), HH - 1);
            int mx = X0 - 4 + lxc * 4;
            const float* p = sb + ch * SP + (mz * HH + my) * WW;
            v4f v;
            if (mx >= 0 && mx <= WW - 4) {
                v = *reinterpret_cast<const v4f*>(p + mx);
            } else {                                  // volume x-edge chunks only
                v.x = p[min(max(mx,     0), WW - 1)];
                v.y = p[min(max(mx + 1, 0), WW - 1)];
                v.z = p[min(max(mx + 2, 0), WW - 1)];
                v.w = p[min(max(mx + 3, 0), WW - 1)];
            }
            vals[i]  = v;
            laddr[i] = ch * REGC + (lz * RYH + ly) * RXW + lxc * 4;
        } else {
            laddr[i] = -1;
        }
    }

    // ---- Flow loads (issued now; stay in flight across the barrier) ----
    int rr = tid >> 3;
    int xi = (tid & 7) << 2;
    int y = Y0 + (rr & 7);
    int z = Z0 + (rr >> 3);
    int x = X0 + xi;
    int fo = b * 3 * SP + (z * HH + y) * WW + x;
    v4f dxv = ld4_nt(flow + fo);
    v4f dyv = ld4_nt(flow + fo + SP);
    v4f dzv = ld4_nt(flow + fo + 2 * SP);

    // ---- LDS writes + barrier ----
    #pragma unroll
    for (int i = 0; i < NITER; ++i)
        if (laddr[i] >= 0)
            *reinterpret_cast<v4f*>(&sbuf[laddr[i]]) = vals[i];
    __syncthreads();

    // ---- Compute 4 samples per thread from LDS ----
    const float* c0 = sbuf;
    const float* c1 = sbuf + REGC;
    int rx0 = X0 - 4, ry0 = Y0 - 3, rz0 = Z0 - 3;

    float a0[4], a1[4];
    #pragma unroll
    for (int j = 0; j < 4; ++j) {
        float dx = dxv[j], dy = dyv[j], dz = dzv[j];
        bool inH = (dx >= -4.0f) & (dx < 4.0f) &
                   (dy >= -3.0f) & (dy < 4.0f) &
                   (dz >= -3.0f) & (dz < 4.0f);
        if (inH) {
            float sx = (float)(x + j) + dx;
            float sy = (float)y + dy;
            float sz = (float)z + dz;
            float xf = floorf(sx), yf = floorf(sy), zf = floorf(sz);
            float fx = sx - xf, fy = sy - yf, fz = sz - zf;
            int x0 = (int)xf, y0 = (int)yf, z0 = (int)zf;
            int x1 = x0 + 1, y1 = y0 + 1, z1 = z0 + 1;

            float wx0 = (x0 >= 0 && x0 < WW) ? (1.0f - fx) : 0.0f;
            float wx1 = (x1 >= 0 && x1 < WW) ? fx : 0.0f;
            float wy0 = (y0 >= 0 && y0 < HH) ? (1.0f - fy) : 0.0f;
            float wy1 = (y1 >= 0 && y1 < HH) ? fy : 0.0f;
            float wz0 = (z0 >= 0 && z0 < DD) ? (1.0f - fz) : 0.0f;
            float wz1 = (z1 >= 0 && z1 < DD) ? fz : 0.0f;

            int cx0 = min(max(x0, 0), WW - 1), cx1 = min(max(x1, 0), WW - 1);
            int cy0 = min(max(y0, 0), HH - 1), cy1 = min(max(y1, 0), HH - 1);
            int cz0 = min(max(z0, 0), DD - 1), cz1 = min(max(z1, 0), DD - 1);

            int pb = cx0 - rx0;          // in [0,38] when inH
            int i1 = cx1 - cx0;          // 0 or 1
            int ly0 = cy0 - ry0, ly1 = cy1 - ry0;   // [0,14]
            int lz0 = cz0 - rz0, lz1 = cz1 - rz0;   // [0,10]

            int o00 = (lz0 * RYH + ly0) * RXW + pb;
            int o01 = (lz0 * RYH + ly1) * RXW + pb;
            int o10 = (lz1 * RYH + ly0) * RXW + pb;
            int o11 = (lz1 * RYH + ly1) * RXW + pb;

            float w00 = wz0 * wy0, w01 = wz0 * wy1;
            float w10 = wz1 * wy0, w11 = wz1 * wy1;

            float p00a = c0[o00], p00b = c0[o00 + 1];
            float q00a = c1[o00], q00b = c1[o00 + 1];
            float p01a = c0[o01], p01b = c0[o01 + 1];
            float q01a = c1[o01], q01b = c1[o01 + 1];
            float p10a = c0[o10], p10b = c0[o10 + 1];
            float q10a = c1[o10], q10b = c1[o10 + 1];
            float p11a = c0[o11], p11b = c0[o11 + 1];
            float q11a = c1[o11], q11b = c1[o11 + 1];

            #define SEL(a_, b_) ((i1) ? (b_) : (a_))
            float r0, r1;
            r0  = w00 * (wx0 * p00a + wx1 * SEL(p00a, p00b));
            r1  = w00 * (wx0 * q00a + wx1 * SEL(q00a, q00b));
            r0 += w01 * (wx0 * p01a + wx1 * SEL(p01a, p01b));
            r1 += w01 * (wx0 * q01a + wx1 * SEL(q01a, q01b));
            r0 += w10 * (wx0 * p10a + wx1 * SEL(p10a, p10b));
            r1 += w10 * (wx0 * q10a + wx1 * SEL(q10a, q10b));
            r0 += w11 * (wx0 * p11a + wx1 * SEL(p11a, p11b));
            r1 += w11 * (wx0 * q11a + wx1 * SEL(q11a, q11b));
            #undef SEL
            a0[j] = r0; a1[j] = r1;
        } else {
            // Rare (~0.3% of samples): displacement outside staged halo (or NaN).
            sample_global(sb, s1g, x + j, y, z, dx, dy, dz, a0[j], a1[j]);
        }
    }

    int oo = b * NC * SP + (z * HH + y) * WW + x;
    v4f o0 = {a0[0], a0[1], a0[2], a0[3]};
    v4f o1 = {a1[0], a1[1], a1[2], a1[3]};
    st4_nt(out + oo, o0);
    st4_nt(out + oo + SP, o1);
}

extern "C" void kernel_launch(void* const* d_in, const int* in_sizes, int n_in,
                              void* d_out, int out_size, void* d_ws, size_t ws_size,
                              hipStream_t stream) {
    const float* src  = (const float*)d_in[0];
    const float* flow = (const float*)d_in[1];
    float* out = (float*)d_out;

    st_warp_kernel<<<NTILES, 256, 0, stream>>>(src, flow, out);
}

// Round 5
// 273.630 us; speedup vs baseline: 1.4535x; 1.0227x over previous
//
#include <hip/hip_runtime.h>

// SIZE = (D,H,W) = (160,192,160), B=2, C=2.
#define DD 160
#define HH 192
#define WW 160
#define SP (DD * HH * WW)
#define NB 2
#define NC 2

// Tile per block and staged (edge-replicated) region.
#define TX 32
#define TY 8
#define TZ 4
#define RXW 40                 // x: [X0-4, X0+35]  supports dx in [-4,4)
#define RYH 15                 // y: [Y0-3, Y0+11]  supports dy in [-3,4)
#define RZD 11                 // z: [Z0-3, Z0+7]   supports dz in [-3,4)
#define REGC (RZD * RYH * RXW) // 6600 voxels; LDS = 2ch*4B*6600 = 52.8 KB
#define NCHUNK (REGC / 4)      // 1650 4-voxel chunks
#define NITER 7                // ceil(1650/256)

#define NTX 5
#define NTY 24
#define NTZ 40
#define NTILES (NTX * NTY * NTZ * NB)   // 9600 blocks
#define PER_XCD (NTILES / 8)

typedef float v2f __attribute__((ext_vector_type(2)));
typedef float v4f __attribute__((ext_vector_type(4)));

__device__ __forceinline__ v4f ld4_nt(const float* p) {
    return __builtin_nontemporal_load(reinterpret_cast<const v4f*>(p));
}
__device__ __forceinline__ void st4_nt(float* p, v4f v) {
    __builtin_nontemporal_store(v, reinterpret_cast<v4f*>(p));
}
__device__ __forceinline__ v2f ld2g(const float* p) {
    return *reinterpret_cast<const v2f*>(p);
}
__device__ __forceinline__ v2f s2(float f) { v2f v = {f, f}; return v; }

// Rare fallback: displacement outside staged halo — full global trilinear.
__device__ __forceinline__ void sample_global(
    const float* __restrict__ s0, const float* __restrict__ s1,
    int x, int y, int z, float dx, float dy, float dz,
    float& a0, float& a1)
{
    float sx = (float)x + dx, sy = (float)y + dy, sz = (float)z + dz;
    float xf = floorf(sx), yf = floorf(sy), zf = floorf(sz);
    float fx = sx - xf, fy = sy - yf, fz = sz - zf;
    int x0 = (int)xf, y0 = (int)yf, z0 = (int)zf;
    int x1 = x0 + 1, y1 = y0 + 1, z1 = z0 + 1;

    float wx0 = (x0 >= 0 && x0 < WW) ? (1.0f - fx) : 0.0f;
    float wx1 = (x1 >= 0 && x1 < WW) ? fx : 0.0f;
    float wy0 = (y0 >= 0 && y0 < HH) ? (1.0f - fy) : 0.0f;
    float wy1 = (y1 >= 0 && y1 < HH) ? fy : 0.0f;
    float wz0 = (z0 >= 0 && z0 < DD) ? (1.0f - fz) : 0.0f;
    float wz1 = (z1 >= 0 && z1 < DD) ? fz : 0.0f;

    int p  = min(max(x0, 0), WW - 2);
    int i0 = min(max(x0, 0), WW - 1) - p;
    int i1 = min(max(x1, 0), WW - 1) - p;
    int cy0 = min(max(y0, 0), HH - 1), cy1 = min(max(y1, 0), HH - 1);
    int cz0 = min(max(z0, 0), DD - 1), cz1 = min(max(z1, 0), DD - 1);

    int o00 = (cz0 * HH + cy0) * WW + p;
    int o01 = (cz0 * HH + cy1) * WW + p;
    int o10 = (cz1 * HH + cy0) * WW + p;
    int o11 = (cz1 * HH + cy1) * WW + p;

    float w00 = wz0 * wy0, w01 = wz0 * wy1, w10 = wz1 * wy0, w11 = wz1 * wy1;

    v2f c0_00 = ld2g(s0 + o00); v2f c1_00 = ld2g(s1 + o00);
    v2f c0_01 = ld2g(s0 + o01); v2f c1_01 = ld2g(s1 + o01);
    v2f c0_10 = ld2g(s0 + o10); v2f c1_10 = ld2g(s1 + o10);
    v2f c0_11 = ld2g(s0 + o11); v2f c1_11 = ld2g(s1 + o11);

    #define PICK(v, i) ((i) ? (v).y : (v).x)
    float r0, r1;
    r0  = w00 * (wx0 * PICK(c0_00, i0) + wx1 * PICK(c0_00, i1));
    r1  = w00 * (wx0 * PICK(c1_00, i0) + wx1 * PICK(c1_00, i1));
    r0 += w01 * (wx0 * PICK(c0_01, i0) + wx1 * PICK(c0_01, i1));
    r1 += w01 * (wx0 * PICK(c1_01, i0) + wx1 * PICK(c1_01, i1));
    r0 += w10 * (wx0 * PICK(c0_10, i0) + wx1 * PICK(c0_10, i1));
    r1 += w10 * (wx0 * PICK(c1_10, i0) + wx1 * PICK(c1_10, i1));
    r0 += w11 * (wx0 * PICK(c0_11, i0) + wx1 * PICK(c0_11, i1));
    r1 += w11 * (wx0 * PICK(c1_11, i0) + wx1 * PICK(c1_11, i1));
    #undef PICK
    a0 = r0; a1 = r1;
}

__global__ __launch_bounds__(256, 3) void st_warp_kernel(
    const float* __restrict__ src,   // [B, C, D, H, W]
    const float* __restrict__ flow,  // [B, 3, D, H, W]
    float* __restrict__ out)         // [B, C, D, H, W]
{
    // Channel-interleaved staged region: sbuf[2*v] = c0, sbuf[2*v+1] = c1.
    __shared__ float sbuf[2 * REGC];   // 52,800 B -> 3 blocks/CU

    int u   = blockIdx.x;
    int tl  = (u & 7) * PER_XCD + (u >> 3);   // XCD-contiguous tile ranges
    int tx  = tl % NTX;  int t2 = tl / NTX;
    int ty  = t2 % NTY;  int t3 = t2 / NTY;
    int tz  = t3 % NTZ;  int b  = t3 / NTZ;
    int X0 = tx * TX, Y0 = ty * TY, Z0 = tz * TZ;
    int tid = threadIdx.x;

    const float* sb = src + b * NC * SP;   // channel 0 base (c1 at +SP)

    // ---- Stage region: issue all global loads first (deep MLP) ----
    v4f va[NITER], vb[NITER];
    int  ad[NITER];
    #pragma unroll
    for (int i = 0; i < NITER; ++i) {
        int c = tid + i * 256;
        if (i < NITER - 1 || c < NCHUNK) {
            int lz  = c / 150;  int r2 = c - lz * 150;   // 150 = RYH*RXW/4
            int ly  = r2 / 10;  int lxc = r2 - ly * 10;  // 10 = RXW/4
            int mz = min(max(Z0 - 3 + lz, 0), DD - 1);
            int my = min(max(Y0 - 3 + ly, 0), HH - 1);
            int mx = X0 - 4 + lxc * 4;
            const float* p = sb + (mz * HH + my) * WW;
            v4f A, B;
            if (mx >= 0 && mx <= WW - 4) {
                A = *reinterpret_cast<const v4f*>(p + mx);
                B = *reinterpret_cast<const v4f*>(p + SP + mx);
            } else {   // volume x-edge chunks only
                int m0 = min(max(mx,     0), WW - 1);
                int m1 = min(max(mx + 1, 0), WW - 1);
                int m2 = min(max(mx + 2, 0), WW - 1);
                int m3 = min(max(mx + 3, 0), WW - 1);
                A.x = p[m0]; A.y = p[m1]; A.z = p[m2]; A.w = p[m3];
                B.x = p[SP + m0]; B.y = p[SP + m1]; B.z = p[SP + m2]; B.w = p[SP + m3];
            }
            va[i] = A; vb[i] = B;
            ad[i] = 2 * ((lz * RYH + ly) * RXW + lxc * 4);  // 32B-aligned
        } else {
            ad[i] = -1;
        }
    }

    // ---- Flow loads (in flight across the barrier) ----
    int rr = tid >> 3;
    int xi = (tid & 7) << 2;
    int yl = rr & 7, zl = rr >> 3;
    int y = Y0 + yl, z = Z0 + zl, x = X0 + xi;
    int fo = b * 3 * SP + (z * HH + y) * WW + x;
    v4f dxv = ld4_nt(flow + fo);
    v4f dyv = ld4_nt(flow + fo + SP);
    v4f dzv = ld4_nt(flow + fo + 2 * SP);

    // ---- Interleave channels, write LDS (2x b128 per chunk) ----
    #pragma unroll
    for (int i = 0; i < NITER; ++i) {
        if (ad[i] >= 0) {
            v4f w0 = {va[i].x, vb[i].x, va[i].y, vb[i].y};
            v4f w1 = {va[i].z, vb[i].z, va[i].w, vb[i].w};
            *reinterpret_cast<v4f*>(&sbuf[ad[i]])     = w0;
            *reinterpret_cast<v4f*>(&sbuf[ad[i] + 4]) = w1;
        }
    }
    __syncthreads();

    // ---- Compute 4 samples/thread from LDS ----
    const int rx0 = X0 - 4, ry0 = Y0 - 3, rz0 = Z0 - 3;
    float a0[4], a1[4];
    #pragma unroll
    for (int j = 0; j < 4; ++j) {
        float dx = dxv[j], dy = dyv[j], dz = dzv[j];
        bool inH = (dx >= -4.0f) & (dx < 4.0f) &
                   (dy >= -3.0f) & (dy < 4.0f) &
                   (dz >= -3.0f) & (dz < 4.0f);
        if (inH) {
            // Region-local coordinates (always in-bounds under inH).
            float lx = (float)(xi + j + 4) + dx;
            float ly = (float)(yl + 3) + dy;
            float lz = (float)(zl + 3) + dz;
            float xf = floorf(lx), yf = floorf(ly), zf = floorf(lz);
            float fx = lx - xf, fy = ly - yf, fz = lz - zf;
            int ix = (int)xf, iy = (int)yf, iz = (int)zf;

            // Zero-weight masks vs volume bounds (values come edge-replicated
            // from LDS — no index clamping needed, staged data already clamped).
            int vx0 = ix + rx0, vy0 = iy + ry0, vz0 = iz + rz0;
            float wx0 = (vx0 >= 0  && vx0 < WW)     ? (1.0f - fx) : 0.0f;
            float wx1 = (vx0 >= -1 && vx0 < WW - 1) ? fx          : 0.0f;
            float wy0 = (vy0 >= 0  && vy0 < HH)     ? (1.0f - fy) : 0.0f;
            float wy1 = (vy0 >= -1 && vy0 < HH - 1) ? fy          : 0.0f;
            float wz0 = (vz0 >= 0  && vz0 < DD)     ? (1.0f - fz) : 0.0f;
            float wz1 = (vz0 >= -1 && vz0 < DD - 1) ? fz          : 0.0f;

            const float* pB = sbuf + 2 * ((iz * RYH + iy) * RXW + ix);
            // Each corner: both channels + both x in two adjacent 8B reads
            // (-> ds_read2_b64).
            v2f A00 = *(const v2f*)(pB);
            v2f B00 = *(const v2f*)(pB + 2);
            v2f A01 = *(const v2f*)(pB + 2 * RXW);
            v2f B01 = *(const v2f*)(pB + 2 * RXW + 2);
            const float* pC = pB + 2 * RYH * RXW;
            v2f A10 = *(const v2f*)(pC);
            v2f B10 = *(const v2f*)(pC + 2);
            v2f A11 = *(const v2f*)(pC + 2 * RXW);
            v2f B11 = *(const v2f*)(pC + 2 * RXW + 2);

            v2f c00 = s2(wx0) * A00 + s2(wx1) * B00;
            v2f c01 = s2(wx0) * A01 + s2(wx1) * B01;
            v2f c10 = s2(wx0) * A10 + s2(wx1) * B10;
            v2f c11 = s2(wx0) * A11 + s2(wx1) * B11;
            v2f m0  = s2(wy0) * c00 + s2(wy1) * c01;
            v2f m1  = s2(wy0) * c10 + s2(wy1) * c11;
            v2f r   = s2(wz0) * m0  + s2(wz1) * m1;
            a0[j] = r.x; a1[j] = r.y;
        } else {
            // ~0.3% of samples: outside staged halo (or NaN).
            sample_global(sb, sb + SP, x + j, y, z, dx, dy, dz, a0[j], a1[j]);
        }
    }

    int oo = b * NC * SP + (z * HH + y) * WW + x;
    v4f o0 = {a0[0], a0[1], a0[2], a0[3]};
    v4f o1 = {a1[0], a1[1], a1[2], a1[3]};
    st4_nt(out + oo, o0);
    st4_nt(out + oo + SP, o1);
}

extern "C" void kernel_launch(void* const* d_in, const int* in_sizes, int n_in,
                              void* d_out, int out_size, void* d_ws, size_t ws_size,
                              hipStream_t stream) {
    const float* src  = (const float*)d_in[0];
    const float* flow = (const float*)d_in[1];
    float* out = (float*)d_out;

    st_warp_kernel<<<NTILES, 256, 0, stream>>>(src, flow, out);
}